// Round 1
// baseline (4907.893 us; speedup 1.0000x reference)
//
#include <hip/hip_runtime.h>

#define TPB 256
#define NB 16
#define TSTEPS 512

#define LD4(p) (*reinterpret_cast<const float4*>(p))
#define ST4(p, v) (*reinterpret_cast<float4*>(p) = (v))

// ---- LDS layout (float offsets) ----
#define OFF_HS   0                  // [64][20]  h, k-major, padded
#define OFF_HS2  1280               // [16][64]  h, b-major
#define OFF_WT   2304               // [64][256] Whh^T (k-major)
#define OFF_WI   (OFF_WT + 16384)   // [16][256] Wih^T (i-major)
#define OFF_BI   (OFF_WI + 4096)    // [256] bias
#define OFF_PH   (OFF_BI + 256)     // phase-specific region
#define OFF_XS     OFF_PH               // enc: [16][16][20] = 5120
#define OFF_GATESE (OFF_XS + 5120)      // enc: [16][256] = 4096
#define OFF_HEADP  OFF_PH               // dec: [16][68] = 1088
#define OFF_HB     (OFF_HEADP + 1088)   // dec: [16]
#define OFF_PS     (OFF_HB + 16)        // dec: [16][20] = 320
#define OFF_GATESD (OFF_PS + 320)       // dec: [16][256] = 4096
#define SMEM_FLOATS (OFF_GATESE + 4096) // 32256 floats = 129024 B
#define SMEM_BYTES  (SMEM_FLOATS * 4)

__device__ __forceinline__ float fast_rcp(float x) {
  float r; asm("v_rcp_f32 %0, %1" : "=v"(r) : "v"(x)); return r;
}
__device__ __forceinline__ float sigf(float x) {
  return fast_rcp(1.f + __expf(-x));
}
__device__ __forceinline__ float tanh_f(float x) {
  float y = fminf(fmaxf(x, -15.f), 15.f);
  float e = __expf(2.f * y);
  return (e - 1.f) * fast_rcp(e + 1.f);
}

// 4x4 outer-product FMA block: a[r][c] += xv[r] * wv[c]
#define FMA16() do { \
  a[0][0]+=xv.x*wv.x; a[0][1]+=xv.x*wv.y; a[0][2]+=xv.x*wv.z; a[0][3]+=xv.x*wv.w; \
  a[1][0]+=xv.y*wv.x; a[1][1]+=xv.y*wv.y; a[1][2]+=xv.y*wv.z; a[1][3]+=xv.y*wv.w; \
  a[2][0]+=xv.z*wv.x; a[2][1]+=xv.z*wv.y; a[2][2]+=xv.z*wv.z; a[2][3]+=xv.z*wv.w; \
  a[3][0]+=xv.w*wv.x; a[3][1]+=xv.w*wv.y; a[3][2]+=xv.w*wv.z; a[3][3]+=xv.w*wv.w; \
} while (0)

// LSTM cell for this thread's 4 cells (b = bc, j = j0..j0+3); c-state in regs.
#define CELL_UPDATE(GATES) do { \
  const float4 gi_ = LD4((GATES) + bc*256 +   0 + j0); \
  const float4 gf_ = LD4((GATES) + bc*256 +  64 + j0); \
  const float4 gg_ = LD4((GATES) + bc*256 + 128 + j0); \
  const float4 go_ = LD4((GATES) + bc*256 + 192 + j0); \
  cc0 = sigf(gf_.x)*cc0 + sigf(gi_.x)*tanh_f(gg_.x); \
  cc1 = sigf(gf_.y)*cc1 + sigf(gi_.y)*tanh_f(gg_.y); \
  cc2 = sigf(gf_.z)*cc2 + sigf(gi_.z)*tanh_f(gg_.z); \
  cc3 = sigf(gf_.w)*cc3 + sigf(gi_.w)*tanh_f(gg_.w); \
  const float h0_ = sigf(go_.x)*tanh_f(cc0); \
  const float h1_ = sigf(go_.y)*tanh_f(cc1); \
  const float h2_ = sigf(go_.z)*tanh_f(cc2); \
  const float h3_ = sigf(go_.w)*tanh_f(cc3); \
  hs[(j0+0)*20 + bc] = h0_; \
  hs[(j0+1)*20 + bc] = h1_; \
  hs[(j0+2)*20 + bc] = h2_; \
  hs[(j0+3)*20 + bc] = h3_; \
  ST4(hs2 + bc*64 + j0, make_float4(h0_, h1_, h2_, h3_)); \
} while (0)

__global__ void __launch_bounds__(TPB) lstm_seq2seq(
    const float* __restrict__ X,    const float* __restrict__ eWih,
    const float* __restrict__ eWhh, const float* __restrict__ eb,
    const float* __restrict__ dWih, const float* __restrict__ dWhh,
    const float* __restrict__ db,   const float* __restrict__ hW,
    const float* __restrict__ hb,   float* __restrict__ out)
{
  extern __shared__ float sm[];
  const int tid = threadIdx.x;
  const int b0g = blockIdx.x * NB;

  // GEMM tile mapping: waves differ in COLUMN block (g0), batch rows inside wave
  // -> per-k weight read is only 256B/wave + 4-way broadcast (LDS-cheap).
  const int w  = tid >> 6, l = tid & 63;
  const int g0  = (w * 16 + (l & 15)) * 4;  // gate column 0..255, x4
  const int b0r = (l >> 4) * 4;             // batch row 0..15, x4
  // cell mapping: thread owns cells (bc, j0..j0+3)
  const int bc = tid >> 4;
  const int j0 = (tid & 15) * 4;

  float* hs  = sm + OFF_HS;
  float* hs2 = sm + OFF_HS2;
  float* WT  = sm + OFF_WT;
  float* WI  = sm + OFF_WI;
  float* BI  = sm + OFF_BI;

  // ---------------- stage encoder weights ----------------
  for (int n4 = tid; n4 < 4096; n4 += TPB) {       // WT[k][g] = eWhh[g][k]
    const int g = n4 >> 4, k4 = n4 & 15;
    const float4 v = LD4(eWhh + g * 64 + k4 * 4);
    WT[(4*k4+0)*256 + g] = v.x; WT[(4*k4+1)*256 + g] = v.y;
    WT[(4*k4+2)*256 + g] = v.z; WT[(4*k4+3)*256 + g] = v.w;
  }
  for (int n4 = tid; n4 < 1024; n4 += TPB) {       // WI[i][g] = eWih[g][i]
    const int g = n4 >> 2, i4 = n4 & 3;
    const float4 v = LD4(eWih + g * 16 + i4 * 4);
    WI[(4*i4+0)*256 + g] = v.x; WI[(4*i4+1)*256 + g] = v.y;
    WI[(4*i4+2)*256 + g] = v.z; WI[(4*i4+3)*256 + g] = v.w;
  }
  BI[tid] = eb[tid];
  for (int n = tid; n < 1280; n += TPB) hs[n]  = 0.f;
  for (int n = tid; n < 1024; n += TPB) hs2[n] = 0.f;

  float cc0 = 0.f, cc1 = 0.f, cc2 = 0.f, cc3 = 0.f;  // this thread's 4 c-states

  // ---------------- encoder: 512 steps ----------------
  {
    float* xs    = sm + OFF_XS;
    float* gates = sm + OFF_GATESE;
    for (int t = 0; t < TSTEPS; ++t) {
      const int tt = t & 15;
      if (tt == 0) {
        // stage X[b0g..+16][t..t+16][:], transposed to xs[ts][i][b] (stride 20)
        #pragma unroll
        for (int r = 0; r < 4; ++r) {
          const int n4 = tid + TPB * r;
          const int bb = n4 >> 6, q4 = n4 & 63;
          const int ts = q4 >> 2, i4 = q4 & 3;
          const float4 v = LD4(X + ((size_t)(b0g + bb) * TSTEPS + (t + ts)) * 16 + i4 * 4);
          xs[(ts*16 + 4*i4+0)*20 + bb] = v.x; xs[(ts*16 + 4*i4+1)*20 + bb] = v.y;
          xs[(ts*16 + 4*i4+2)*20 + bb] = v.z; xs[(ts*16 + 4*i4+3)*20 + bb] = v.w;
        }
        __syncthreads();
      }
      // gates = bias + x*WihT + h*WhhT  (4x4 register tile per thread)
      float a[4][4];
      {
        const float4 bv = LD4(BI + g0);
        #pragma unroll
        for (int r = 0; r < 4; ++r) { a[r][0]=bv.x; a[r][1]=bv.y; a[r][2]=bv.z; a[r][3]=bv.w; }
      }
      const float* xrow = xs + tt * 320;
      #pragma unroll
      for (int i = 0; i < 16; ++i) {
        const float4 xv = LD4(xrow + i*20 + b0r);
        const float4 wv = LD4(WI + i*256 + g0);
        FMA16();
      }
      #pragma unroll 16
      for (int k = 0; k < 64; ++k) {
        const float4 xv = LD4(hs + k*20 + b0r);
        const float4 wv = LD4(WT + k*256 + g0);
        FMA16();
      }
      #pragma unroll
      for (int r = 0; r < 4; ++r)
        ST4(gates + (b0r + r)*256 + g0, make_float4(a[r][0], a[r][1], a[r][2], a[r][3]));
      __syncthreads();
      CELL_UPDATE(gates);
      __syncthreads();
    }
  }

  // ---------------- stage decoder weights ----------------
  float* headp = sm + OFF_HEADP;
  float* hbs   = sm + OFF_HB;
  float* ps    = sm + OFF_PS;
  {
    for (int n4 = tid; n4 < 4096; n4 += TPB) {
      const int g = n4 >> 4, k4 = n4 & 15;
      const float4 v = LD4(dWhh + g * 64 + k4 * 4);
      WT[(4*k4+0)*256 + g] = v.x; WT[(4*k4+1)*256 + g] = v.y;
      WT[(4*k4+2)*256 + g] = v.z; WT[(4*k4+3)*256 + g] = v.w;
    }
    for (int n4 = tid; n4 < 1024; n4 += TPB) {
      const int g = n4 >> 2, i4 = n4 & 3;
      const float4 v = LD4(dWih + g * 16 + i4 * 4);
      WI[(4*i4+0)*256 + g] = v.x; WI[(4*i4+1)*256 + g] = v.y;
      WI[(4*i4+2)*256 + g] = v.z; WI[(4*i4+3)*256 + g] = v.w;
    }
    BI[tid] = db[tid];
    for (int n4 = tid; n4 < 256; n4 += TPB) {      // headp[o][k] = hW[o][k] (stride 68)
      const int o = n4 >> 4, k4 = n4 & 15;
      ST4(headp + o*68 + k4*4, LD4(hW + o*64 + k4*4));
    }
    if (tid < 16) hbs[tid] = hb[tid];
    for (int n = tid; n < 320; n += TPB) ps[n] = 0.f;  // BOS prev = 0
    __syncthreads();
  }

  // ---------------- decoder: 512 autoregressive steps ----------------
  {
    float* gates = sm + OFF_GATESD;
    const int bh = tid >> 4, oo = tid & 15;
    for (int t = 0; t < TSTEPS; ++t) {
      float a[4][4];
      {
        const float4 bv = LD4(BI + g0);
        #pragma unroll
        for (int r = 0; r < 4; ++r) { a[r][0]=bv.x; a[r][1]=bv.y; a[r][2]=bv.z; a[r][3]=bv.w; }
      }
      #pragma unroll
      for (int i = 0; i < 16; ++i) {
        const float4 xv = LD4(ps + i*20 + b0r);
        const float4 wv = LD4(WI + i*256 + g0);
        FMA16();
      }
      #pragma unroll 16
      for (int k = 0; k < 64; ++k) {
        const float4 xv = LD4(hs + k*20 + b0r);
        const float4 wv = LD4(WT + k*256 + g0);
        FMA16();
      }
      #pragma unroll
      for (int r = 0; r < 4; ++r)
        ST4(gates + (b0r + r)*256 + g0, make_float4(a[r][0], a[r][1], a[r][2], a[r][3]));
      __syncthreads();
      CELL_UPDATE(gates);
      __syncthreads();
      // head: pred[b][o] = h_new[b] . hW[o] + hb[o]; emit + feed back
      float acc = hbs[oo];
      #pragma unroll
      for (int k4 = 0; k4 < 16; ++k4) {
        const float4 hv = LD4(hs2 + bh*64 + k4*4);
        const float4 wv = LD4(headp + oo*68 + k4*4);
        acc += hv.x*wv.x + hv.y*wv.y + hv.z*wv.z + hv.w*wv.w;
      }
      out[((size_t)(b0g + bh) * TSTEPS + t) * 16 + oo] = acc;
      ps[oo*20 + bh] = acc;
      __syncthreads();
    }
  }
}

extern "C" void kernel_launch(void* const* d_in, const int* in_sizes, int n_in,
                              void* d_out, int out_size, void* d_ws, size_t ws_size,
                              hipStream_t stream) {
  (void)in_sizes; (void)n_in; (void)d_ws; (void)ws_size; (void)out_size;
  const float* X    = (const float*)d_in[0];
  const float* eWih = (const float*)d_in[1];
  const float* eWhh = (const float*)d_in[2];
  const float* eb   = (const float*)d_in[3];
  const float* dWih = (const float*)d_in[4];
  const float* dWhh = (const float*)d_in[5];
  const float* db   = (const float*)d_in[6];
  const float* hW   = (const float*)d_in[7];
  const float* hb   = (const float*)d_in[8];
  float* out = (float*)d_out;

  // >64KB dynamic LDS opt-in (idempotent, host-side: graph-capture safe)
  hipFuncSetAttribute(reinterpret_cast<const void*>(lstm_seq2seq),
                      hipFuncAttributeMaxDynamicSharedMemorySize, SMEM_BYTES);
  lstm_seq2seq<<<dim3(256), dim3(TPB), SMEM_BYTES, stream>>>(
      X, eWih, eWhh, eb, dWih, dWhh, db, hW, hb, out);
}